// Round 2
// baseline (306.841 us; speedup 1.0000x reference)
//
#include <hip/hip_runtime.h>
#include <hip/hip_bf16.h>
#include <stdint.h>

#define LQ 1024
#define BQ 2
#define AQ 14
#define KQ 30
#define EFQ 128
#define EDGE_IN 3152
#define KPAD 3200
#define NCHUNK 50
#define MTILE 128
#define ROWS (BQ*LQ*KQ)            /* 61440 */
#define EIDX_OFF (ROWS*EFQ)        /* 7864320 */

typedef __attribute__((ext_vector_type(8))) _Float16 half8;
typedef __attribute__((ext_vector_type(2))) _Float16 half2t;
typedef __attribute__((ext_vector_type(4))) float floatx4;
typedef unsigned long long ull;

static __device__ __forceinline__ uint32_t pkh(float a, float b) {
    auto h = __builtin_amdgcn_cvt_pkrtz(a, b);   // __fp16 ext_vector(2)
    return __builtin_bit_cast(uint32_t, h);
}
static __device__ __forceinline__ ull umin64(ull a, ull b) { return a < b ? a : b; }

// ---------------------------------------------------------------------------
// Kernel A v6 (unchanged): blocks 0..255 topk (8 rows/block, one wave per row,
// u64-packed keys); blocks 256..305: W fp32 -> f16 padded copy.
// ---------------------------------------------------------------------------
__global__ __launch_bounds__(512) void topk_kernel(
    const float* __restrict__ X, const float* __restrict__ mask,
    const float* __restrict__ W, float* __restrict__ out,
    int* __restrict__ idx_ws, _Float16* __restrict__ wpad)
{
    __shared__ float xs[LQ], ys[LQ], zs[LQ], ms[LQ];
    const int t = threadIdx.x;

    if (blockIdx.x >= 256) {                    // ---- merged wpad ----
        int base = (blockIdx.x - 256)*8192 + t; // 50 blocks x 8192 = 409600 exact
        #pragma unroll
        for (int r = 0; r < 16; ++r) {
            int idx = base + r*512;
            int n = idx / KPAD, f = idx - n*KPAD;
            float v = (f < EDGE_IN) ? W[(size_t)n*EDGE_IN + f] : 0.0f;
            wpad[idx] = (_Float16)v;
        }
        return;
    }

    const int w = t >> 6, lane = t & 63;
    const int row = blockIdx.x*8 + w;           // same b for whole block
    const int b = row >> 10, i = row & (LQ - 1);

    for (int j = t; j < LQ; j += 512) {
        size_t base = ((size_t)(b*LQ + j))*42 + 3;   // atom 1 (CA)
        xs[j] = X[base+0]; ys[j] = X[base+1]; zs[j] = X[base+2];
        ms[j] = mask[b*LQ + j];
    }
    __syncthreads();

    const float mif = ms[i];
    const double cx = (double)xs[i], cy = (double)ys[i], cz = (double)zs[i];

    double Dk[16]; float mf[16];
    bool allone = (mif == 1.0f);
    #pragma unroll
    for (int s = 0; s < 16; ++s) {
        int j = s*64 + lane;
        double dx = __dsub_rn(cx, (double)xs[j]);
        double dy = __dsub_rn(cy, (double)ys[j]);
        double dz = __dsub_rn(cz, (double)zs[j]);
        mf[s] = ms[j];
        Dk[s] = __dadd_rn(__dadd_rn(__dmul_rn(dx,dx), __dmul_rn(dy,dy)),
                          __dmul_rn(dz,dz));
        allone = allone && (mf[s] == 1.0f);
    }

    if (!__all(allone ? 1 : 0)) {
        // exact general path: D = mi*mj*sqrt(ssq+1e-6); key = D + 2(1-m2)*max(D)
        const double mi_d = (double)mif;
        double lm = 0.0;
        #pragma unroll
        for (int s = 0; s < 16; ++s) {
            double m2 = __dmul_rn(mi_d, (double)mf[s]);
            Dk[s] = __dmul_rn(m2, sqrt(__dadd_rn(Dk[s], 1e-6)));
            lm = fmax(lm, Dk[s]);
        }
        #pragma unroll
        for (int off = 32; off; off >>= 1) lm = fmax(lm, __shfl_xor(lm, off));
        #pragma unroll
        for (int s = 0; s < 16; ++s) {
            double m2 = __dmul_rn(mi_d, (double)mf[s]);
            Dk[s] = __dadd_rn(Dk[s],
                    __dmul_rn(__dmul_rn(2.0, __dsub_rn(1.0, m2)), lm));
        }
    }

    ull key[16];
    #pragma unroll
    for (int s = 0; s < 16; ++s)
        key[s] = (((ull)__double_as_longlong(Dk[s])) & ~1023ull)
               | (unsigned)(s*64 + lane);

    for (int k = 0; k < KQ; ++k) {
        ull a0 = umin64(key[0],  key[1]),  a1 = umin64(key[2],  key[3]);
        ull a2 = umin64(key[4],  key[5]),  a3 = umin64(key[6],  key[7]);
        ull a4 = umin64(key[8],  key[9]),  a5 = umin64(key[10], key[11]);
        ull a6 = umin64(key[12], key[13]), a7 = umin64(key[14], key[15]);
        ull b0 = umin64(a0, a1), b1 = umin64(a2, a3);
        ull b2 = umin64(a4, a5), b3 = umin64(a6, a7);
        ull bk = umin64(umin64(b0, b1), umin64(b2, b3));
        #pragma unroll
        for (int off = 32; off; off >>= 1)
            bk = umin64(bk, (ull)__shfl_xor(bk, off));
        int j = (int)(bk & 1023ull);
        if (lane == 0) {
            int rg = row*KQ + k;
            idx_ws[rg] = j;
            out[EIDX_OFF + rg] = (float)j;
        }
        bool mine = ((j & 63) == lane);
        int s_win = j >> 6;
        #pragma unroll
        for (int s = 0; s < 16; ++s)
            key[s] = (mine && s == s_win) ? ~0ull : key[s];
    }
}

// ---------------------------------------------------------------------------
// Kernel B v9: fused feature-gen + f16 MFMA GEMM + LayerNorm.
// BARRIER-FREE K-loop: B fragments are loaded straight from global (wpad is
// 800 KB -> L2-resident per XCD) into registers; no LDS staging of B, no
// per-chunk __syncthreads. 256 threads, 4 waves x 32 rows. LDS 32.2 KB ->
// 4 blocks/CU (16 waves/CU) with __launch_bounds__(256,4).
// ---------------------------------------------------------------------------
struct FusedSmem {
    alignas(16) unsigned short atoms[256*56];  // f16 x,y,z,pad x 14 slots; 0..127 center, 128..255 neighbor
    alignas(16) float drow[MTILE];
    int residg[256];
    unsigned int maskb[256];
    float gsh[EFQ], bsh[EFQ];
};                                             // 32,256 B -> 4 blocks/CU

// Generate 8 contiguous features [f0, f0+8) for one row as 4 packed f16
// dwords. RBF: exp(-((d - r*4/3)*0.8)^2) = exp2(-(u - r*v)^2),
// u = d*0.96089846, v = 1.28119795. Dead pairs (mask or pad) poison u so all
// eight exp2 underflow to exact +0.
static __device__ __forceinline__ void gen8(
    const unsigned short* __restrict__ atomsA,
    const unsigned short* __restrict__ atomsB,
    unsigned maskA, unsigned maskB, float drowv,
    int f0, uint32_t* __restrict__ v)
{
    if (f0 >= 16) {
        int p = (f0 - 16) >> 4;
        int rbase = (f0 - 16) & 15;                 // == (q&1)*8
        int pc = p > 195 ? 195 : p;                 // clamp pad region to valid slot
        int a  = (pc * 74899) >> 20;                // pc / 14 for pc < 2048
        int bp = pc - a*14;
        bool dead = (p > 195) |
                    ((((maskA >> a) | (maskB >> bp)) & 1u) != 0u);
        half2t c0 = *reinterpret_cast<const half2t*>(atomsA + a*4);
        half2t c1 = *reinterpret_cast<const half2t*>(atomsA + a*4 + 2);
        half2t n0 = *reinterpret_cast<const half2t*>(atomsB + bp*4);
        half2t n1 = *reinterpret_cast<const half2t*>(atomsB + bp*4 + 2);
        half2t dxy = c0 - n0;                        // v_pk_add_f16
        half2t dzw = c1 - n1;
        float dx = (float)dxy[0], dy = (float)dxy[1], dz = (float)dzw[0];
        float u = __builtin_amdgcn_sqrtf(dx*dx + dy*dy + dz*dz + 1e-6f) * 0.96089846f;
        u = dead ? 1.0e4f : u;                       // exp2(-(~1e4)^2) -> +0 exactly
        #pragma unroll
        for (int k = 0; k < 4; ++k) {
            float t0 = __fmaf_rn(-(float)(rbase + 2*k),     1.28119795f, u);
            float t1 = __fmaf_rn(-(float)(rbase + 2*k + 1), 1.28119795f, u);
            v[k] = pkh(__builtin_amdgcn_exp2f(-(t0*t0)),
                       __builtin_amdgcn_exp2f(-(t1*t1)));
        }
    } else {
        const float fr[8] = {1.0f, 0.31622776601683794f, 0.1f,
            0.031622776601683794f, 0.01f, 0.0031622776601683794f,
            0.001f, 0.00031622776601683794f};
        float e[8];
        if (f0 == 0) {
            #pragma unroll
            for (int j = 0; j < 8; ++j) e[j] = __cosf(drowv * fr[j]);
        } else {
            #pragma unroll
            for (int j = 0; j < 8; ++j) e[j] = __sinf(drowv * fr[j]);
        }
        #pragma unroll
        for (int k = 0; k < 4; ++k) v[k] = pkh(e[2*k], e[2*k+1]);
    }
}

__global__ __launch_bounds__(256, 4) void fused_kernel(
    const float* __restrict__ X, const float* __restrict__ atom_mask,
    const _Float16* __restrict__ wpad, const float* __restrict__ gamma,
    const float* __restrict__ beta, const int* __restrict__ idx_ws,
    float* __restrict__ out)
{
    __shared__ FusedSmem sm;
    const int t = threadIdx.x;               // 0..255
    const int row0 = blockIdx.x * MTILE;
    const int b = row0 / (LQ*KQ);            // tiles never straddle b (30720 % 128 == 0)

    if (t < MTILE) {
        int rg = row0 + t;
        int rem = rg - b*(LQ*KQ);
        int i = rem / KQ;
        int j = idx_ws[rg];
        sm.residg[t]       = b*LQ + i;
        sm.residg[MTILE+t] = b*LQ + j;
        sm.drow[t] = (float)j - (float)i;
    }
    if (t < EFQ) { sm.gsh[t] = gamma[t]; sm.bsh[t] = beta[t]; }
    __syncthreads();

    // stage atoms: fp32 global -> packed f16 LDS (x,y,z,0 per slot)
    for (int u2 = t; u2 < 256*14; u2 += 256) {   // 14 exact iterations
        int s = u2 / 14; int a = u2 - s*14;
        const float* xp = X + (size_t)sm.residg[s]*42 + a*3;
        uint2 pk; pk.x = pkh(xp[0], xp[1]); pk.y = pkh(xp[2], 0.0f);
        *reinterpret_cast<uint2*>(&sm.atoms[s*56 + a*4]) = pk;
    }
    __syncthreads();

    {   // all 256 threads: Cb into slot 4 + mask bits, one residue each
        unsigned short* at = &sm.atoms[t*56];
        auto ld3 = [&](int slot, float& x, float& y, float& z) {
            half2t p0 = *reinterpret_cast<const half2t*>(at + slot*4);
            half2t p1 = *reinterpret_cast<const half2t*>(at + slot*4 + 2);
            x = (float)p0[0]; y = (float)p0[1]; z = (float)p1[0];
        };
        float Nx,Ny,Nz, Cax,Cay,Caz, Cx,Cy,Cz;
        ld3(0, Nx,Ny,Nz); ld3(1, Cax,Cay,Caz); ld3(2, Cx,Cy,Cz);
        float bx=Cax-Nx, by=Cay-Ny, bz=Caz-Nz;
        float ex=Cx-Cax, ey=Cy-Cay, ez=Cz-Caz;
        float ax = by*ez - bz*ey, ay = bz*ex - bx*ez, az = bx*ey - by*ex;
        float cbx = -0.58273431f*ax + 0.56802827f*bx - 0.54067466f*ex + Cax;
        float cby = -0.58273431f*ay + 0.56802827f*by - 0.54067466f*ey + Cay;
        float cbz = -0.58273431f*az + 0.56802827f*bz - 0.54067466f*ez + Caz;
        uint2 pk; pk.x = pkh(cbx, cby); pk.y = pkh(cbz, 0.0f);
        *reinterpret_cast<uint2*>(at + 4*4) = pk;    // slot 4 = Cb
        unsigned mb = 0;
        const float* amp = &atom_mask[(size_t)sm.residg[t]*AQ];
        #pragma unroll
        for (int a = 0; a < AQ; ++a) if (amp[a] > 0.5f) mb |= (1u << a);
        sm.maskb[t] = mb;
    }

    const int w = t >> 6, lane = t & 63, q = lane >> 4, l15 = lane & 15;
    const int m0 = w*32 + l15, m1 = m0 + 16;  // the wave's two 16-row groups

    // Direct-global B-fragment base pointers (L2-resident wpad):
    // b0 = W[n][c*64 + q*8 .. +7], b1 = W[n][c*64 + 32 + q*8 .. +7],
    // n = nt*16 + l15. 16B-aligned.
    const _Float16* bq = wpad + (size_t)l15*KPAD + q*8;
    const _Float16* bnt[8];
    #pragma unroll
    for (int nt = 0; nt < 8; ++nt) bnt[nt] = bq + (size_t)nt*16*KPAD;

    floatx4 acc0[8], acc1[8];
    #pragma unroll
    for (int nt = 0; nt < 8; ++nt) {
        acc0[nt] = (floatx4){0.f,0.f,0.f,0.f};
        acc1[nt] = (floatx4){0.f,0.f,0.f,0.f};
    }

    __syncthreads();                          // atoms/maskb ready

    const unsigned short* atomsA0 = &sm.atoms[m0*56];
    const unsigned short* atomsB0 = &sm.atoms[(MTILE+m0)*56];
    const unsigned short* atomsA1 = &sm.atoms[m1*56];
    const unsigned short* atomsB1 = &sm.atoms[(MTILE+m1)*56];
    const unsigned maskA0 = sm.maskb[m0], maskB0 = sm.maskb[MTILE+m0];
    const unsigned maskA1 = sm.maskb[m1], maskB1 = sm.maskb[MTILE+m1];
    const float drow0 = sm.drow[m0], drow1 = sm.drow[m1];

    union H8 { uint32_t u[4]; half8 h; };
    // Barrier-free K loop: gen (VALU/TRANS) + global b-loads (L2) + MFMA,
    // self-pipelined by the compiler, overlapped across 16 waves/CU.
    for (int c = 0; c < NCHUNK; ++c) {
        H8 a00, a01, a10, a11;
        gen8(atomsA0, atomsB0, maskA0, maskB0, drow0, c*64 + q*8,      a00.u);
        gen8(atomsA0, atomsB0, maskA0, maskB0, drow0, c*64 + 32 + q*8, a01.u);
        gen8(atomsA1, atomsB1, maskA1, maskB1, drow1, c*64 + q*8,      a10.u);
        gen8(atomsA1, atomsB1, maskA1, maskB1, drow1, c*64 + 32 + q*8, a11.u);
        const int coff = c*64;
        #pragma unroll
        for (int nt = 0; nt < 8; ++nt) {
            half8 b0 = *reinterpret_cast<const half8*>(bnt[nt] + coff);
            half8 b1 = *reinterpret_cast<const half8*>(bnt[nt] + coff + 32);
            acc0[nt] = __builtin_amdgcn_mfma_f32_16x16x32_f16(a00.h, b0, acc0[nt], 0, 0, 0);
            acc0[nt] = __builtin_amdgcn_mfma_f32_16x16x32_f16(a01.h, b1, acc0[nt], 0, 0, 0);
            acc1[nt] = __builtin_amdgcn_mfma_f32_16x16x32_f16(a10.h, b0, acc1[nt], 0, 0, 0);
            acc1[nt] = __builtin_amdgcn_mfma_f32_16x16x32_f16(a11.h, b1, acc1[nt], 0, 0, 0);
        }
    }

    // LayerNorm epilogue. C/D layout: col = lane&15, row = quad*4 + reg.
    auto lnrows = [&](const floatx4* acc, int gbase) {
        #pragma unroll
        for (int v = 0; v < 4; ++v) {
            float s = 0.f, s2 = 0.f;
            #pragma unroll
            for (int nt = 0; nt < 8; ++nt) { float x = acc[nt][v]; s += x; s2 += x*x; }
            #pragma unroll
            for (int off = 1; off < 16; off <<= 1) {
                s  += __shfl_xor(s,  off);
                s2 += __shfl_xor(s2, off);
            }
            float mean = s * (1.0f/128.0f);
            float var  = s2 * (1.0f/128.0f) - mean*mean;
            float rstd = 1.0f / sqrtf(var + 1e-5f);
            int row_l = w*32 + gbase + q*4 + v;
            size_t obase = (size_t)(row0 + row_l)*EFQ;
            #pragma unroll
            for (int nt = 0; nt < 8; ++nt) {
                int col = nt*16 + l15;
                out[obase + col] = (acc[nt][v] - mean)*rstd*sm.gsh[col] + sm.bsh[col];
            }
        }
    };
    lnrows(acc0, 0);
    lnrows(acc1, 16);
}

extern "C" void kernel_launch(void* const* d_in, const int* in_sizes, int n_in,
                              void* d_out, int out_size, void* d_ws, size_t ws_size,
                              hipStream_t stream)
{
    const float* X         = (const float*)d_in[0];
    const float* mask      = (const float*)d_in[1];
    // d_in[2] residue_idx, d_in[3] chain_labels: unused by the reference math
    const float* atom_mask = (const float*)d_in[4];
    const float* W         = (const float*)d_in[5];
    const float* gamma     = (const float*)d_in[6];
    const float* beta      = (const float*)d_in[7];
    float* out = (float*)d_out;

    int*       idx_ws = (int*)d_ws;                               // 61440*4 B
    _Float16*  wpad   = (_Float16*)((char*)d_ws + 262144);        // 128*3200*2 B

    hipLaunchKernelGGL(topk_kernel, dim3(306), dim3(512), 0, stream,
                       X, mask, W, out, idx_ws, wpad);
    hipLaunchKernelGGL(fused_kernel, dim3(ROWS/MTILE), dim3(256), 0, stream,
                       X, atom_mask, wpad, gamma, beta, idx_ws, out);
}

// Round 3
// 220.327 us; speedup vs baseline: 1.3927x; 1.3927x over previous
//
#include <hip/hip_runtime.h>
#include <hip/hip_bf16.h>
#include <stdint.h>

#define LQ 1024
#define BQ 2
#define AQ 14
#define KQ 30
#define EFQ 128
#define EDGE_IN 3152
#define KPAD 3200
#define NCHUNK2 100               /* K-step 32 */
#define MTILE 128
#define ROWS (BQ*LQ*KQ)            /* 61440 */
#define EIDX_OFF (ROWS*EFQ)        /* 7864320 */

typedef __attribute__((ext_vector_type(8))) _Float16 half8;
typedef __attribute__((ext_vector_type(2))) _Float16 half2t;
typedef __attribute__((ext_vector_type(4))) float floatx4;
typedef unsigned long long ull;

static __device__ __forceinline__ uint32_t pkh(float a, float b) {
    auto h = __builtin_amdgcn_cvt_pkrtz(a, b);   // __fp16 ext_vector(2)
    return __builtin_bit_cast(uint32_t, h);
}
static __device__ __forceinline__ ull umin64(ull a, ull b) { return a < b ? a : b; }

// ---------------------------------------------------------------------------
// Kernel A v6 (unchanged): blocks 0..255 topk (8 rows/block, one wave per row,
// u64-packed keys); blocks 256..305: W fp32 -> f16 padded copy.
// ---------------------------------------------------------------------------
__global__ __launch_bounds__(512) void topk_kernel(
    const float* __restrict__ X, const float* __restrict__ mask,
    const float* __restrict__ W, float* __restrict__ out,
    int* __restrict__ idx_ws, _Float16* __restrict__ wpad)
{
    __shared__ float xs[LQ], ys[LQ], zs[LQ], ms[LQ];
    const int t = threadIdx.x;

    if (blockIdx.x >= 256) {                    // ---- merged wpad ----
        int base = (blockIdx.x - 256)*8192 + t; // 50 blocks x 8192 = 409600 exact
        #pragma unroll
        for (int r = 0; r < 16; ++r) {
            int idx = base + r*512;
            int n = idx / KPAD, f = idx - n*KPAD;
            float v = (f < EDGE_IN) ? W[(size_t)n*EDGE_IN + f] : 0.0f;
            wpad[idx] = (_Float16)v;
        }
        return;
    }

    const int w = t >> 6, lane = t & 63;
    const int row = blockIdx.x*8 + w;           // same b for whole block
    const int b = row >> 10, i = row & (LQ - 1);

    for (int j = t; j < LQ; j += 512) {
        size_t base = ((size_t)(b*LQ + j))*42 + 3;   // atom 1 (CA)
        xs[j] = X[base+0]; ys[j] = X[base+1]; zs[j] = X[base+2];
        ms[j] = mask[b*LQ + j];
    }
    __syncthreads();

    const float mif = ms[i];
    const double cx = (double)xs[i], cy = (double)ys[i], cz = (double)zs[i];

    double Dk[16]; float mf[16];
    bool allone = (mif == 1.0f);
    #pragma unroll
    for (int s = 0; s < 16; ++s) {
        int j = s*64 + lane;
        double dx = __dsub_rn(cx, (double)xs[j]);
        double dy = __dsub_rn(cy, (double)ys[j]);
        double dz = __dsub_rn(cz, (double)zs[j]);
        mf[s] = ms[j];
        Dk[s] = __dadd_rn(__dadd_rn(__dmul_rn(dx,dx), __dmul_rn(dy,dy)),
                          __dmul_rn(dz,dz));
        allone = allone && (mf[s] == 1.0f);
    }

    if (!__all(allone ? 1 : 0)) {
        // exact general path: D = mi*mj*sqrt(ssq+1e-6); key = D + 2(1-m2)*max(D)
        const double mi_d = (double)mif;
        double lm = 0.0;
        #pragma unroll
        for (int s = 0; s < 16; ++s) {
            double m2 = __dmul_rn(mi_d, (double)mf[s]);
            Dk[s] = __dmul_rn(m2, sqrt(__dadd_rn(Dk[s], 1e-6)));
            lm = fmax(lm, Dk[s]);
        }
        #pragma unroll
        for (int off = 32; off; off >>= 1) lm = fmax(lm, __shfl_xor(lm, off));
        #pragma unroll
        for (int s = 0; s < 16; ++s) {
            double m2 = __dmul_rn(mi_d, (double)mf[s]);
            Dk[s] = __dadd_rn(Dk[s],
                    __dmul_rn(__dmul_rn(2.0, __dsub_rn(1.0, m2)), lm));
        }
    }

    ull key[16];
    #pragma unroll
    for (int s = 0; s < 16; ++s)
        key[s] = (((ull)__double_as_longlong(Dk[s])) & ~1023ull)
               | (unsigned)(s*64 + lane);

    for (int k = 0; k < KQ; ++k) {
        ull a0 = umin64(key[0],  key[1]),  a1 = umin64(key[2],  key[3]);
        ull a2 = umin64(key[4],  key[5]),  a3 = umin64(key[6],  key[7]);
        ull a4 = umin64(key[8],  key[9]),  a5 = umin64(key[10], key[11]);
        ull a6 = umin64(key[12], key[13]), a7 = umin64(key[14], key[15]);
        ull b0 = umin64(a0, a1), b1 = umin64(a2, a3);
        ull b2 = umin64(a4, a5), b3 = umin64(a6, a7);
        ull bk = umin64(umin64(b0, b1), umin64(b2, b3));
        #pragma unroll
        for (int off = 32; off; off >>= 1)
            bk = umin64(bk, (ull)__shfl_xor(bk, off));
        int j = (int)(bk & 1023ull);
        if (lane == 0) {
            int rg = row*KQ + k;
            idx_ws[rg] = j;
            out[EIDX_OFF + rg] = (float)j;
        }
        bool mine = ((j & 63) == lane);
        int s_win = j >> 6;
        #pragma unroll
        for (int s = 0; s < 16; ++s)
            key[s] = (mine && s == s_win) ? ~0ull : key[s];
    }
}

// ---------------------------------------------------------------------------
// Kernel B v10: fused feature-gen + f16 MFMA GEMM + LayerNorm.
// 512 threads = 8 waves arranged 4 row-groups x 2 col-halves; each wave owns
// 32 rows x 64 cols -> per-chunk B LDS reads halve vs v7 (feature-gen
// duplicates 2x -- VALU has 4x headroom at ~14.5%/SIMD).
// K-step 32, double-buffered Bl, ONE barrier per chunk: stage(c+1) issued
// right after barrier(c); compiler's vmcnt(0)-before-barrier then waits on a
// load issued a full chunk earlier -> L2 latency hidden.
// LDS 50.7 KB -> 3 blocks/CU (24 waves/CU) with __launch_bounds__(512,6).
// ---------------------------------------------------------------------------
struct FusedSmem {
    alignas(16) unsigned short atoms[256*56];  // 28672 B: f16 x,y,z,pad x 14 slots
    alignas(16) unsigned short Bl[2*128*32];   // 16384 B: dbuf W chunk, XOR-swizzled
    alignas(16) float drow[MTILE];             // 512
    alignas(16) float part[MTILE][2];          // 1024: LN partial sums per col-half
    alignas(16) float part2[MTILE][2];         // 1024
    int residg[256];                           // 1024
    unsigned int maskb[256];                   // 1024
    float gsh[EFQ], bsh[EFQ];                  // 1024
};                                             // 50,688 B -> 3 blocks/CU

// Generate 8 contiguous features [f0, f0+8) for one row as 4 packed f16
// dwords. RBF: exp(-((d - r*4/3)*0.8)^2) = exp2(-(u - r*v)^2),
// u = d*0.96089846, v = 1.28119795. Dead pairs (mask or pad) poison u so all
// eight exp2 underflow to exact +0.
static __device__ __forceinline__ void gen8(
    const unsigned short* __restrict__ atomsA,
    const unsigned short* __restrict__ atomsB,
    unsigned maskA, unsigned maskB, float drowv,
    int f0, uint32_t* __restrict__ v)
{
    if (f0 >= 16) {
        int p = (f0 - 16) >> 4;
        int rbase = (f0 - 16) & 15;                 // == (q&1)*8
        int pc = p > 195 ? 195 : p;                 // clamp pad region to valid slot
        int a  = (pc * 74899) >> 20;                // pc / 14 for pc < 2048
        int bp = pc - a*14;
        bool dead = (p > 195) |
                    ((((maskA >> a) | (maskB >> bp)) & 1u) != 0u);
        half2t c0 = *reinterpret_cast<const half2t*>(atomsA + a*4);
        half2t c1 = *reinterpret_cast<const half2t*>(atomsA + a*4 + 2);
        half2t n0 = *reinterpret_cast<const half2t*>(atomsB + bp*4);
        half2t n1 = *reinterpret_cast<const half2t*>(atomsB + bp*4 + 2);
        half2t dxy = c0 - n0;                        // v_pk_add_f16
        half2t dzw = c1 - n1;
        float dx = (float)dxy[0], dy = (float)dxy[1], dz = (float)dzw[0];
        float u = __builtin_amdgcn_sqrtf(dx*dx + dy*dy + dz*dz + 1e-6f) * 0.96089846f;
        u = dead ? 1.0e4f : u;                       // exp2(-(~1e4)^2) -> +0 exactly
        #pragma unroll
        for (int k = 0; k < 4; ++k) {
            float t0 = __fmaf_rn(-(float)(rbase + 2*k),     1.28119795f, u);
            float t1 = __fmaf_rn(-(float)(rbase + 2*k + 1), 1.28119795f, u);
            v[k] = pkh(__builtin_amdgcn_exp2f(-(t0*t0)),
                       __builtin_amdgcn_exp2f(-(t1*t1)));
        }
    } else {
        const float fr[8] = {1.0f, 0.31622776601683794f, 0.1f,
            0.031622776601683794f, 0.01f, 0.0031622776601683794f,
            0.001f, 0.00031622776601683794f};
        float e[8];
        if (f0 == 0) {
            #pragma unroll
            for (int j = 0; j < 8; ++j) e[j] = __cosf(drowv * fr[j]);
        } else {
            #pragma unroll
            for (int j = 0; j < 8; ++j) e[j] = __sinf(drowv * fr[j]);
        }
        #pragma unroll
        for (int k = 0; k < 4; ++k) v[k] = pkh(e[2*k], e[2*k+1]);
    }
}

__global__ __launch_bounds__(512, 6) void fused_kernel(
    const float* __restrict__ X, const float* __restrict__ atom_mask,
    const _Float16* __restrict__ wpad, const float* __restrict__ gamma,
    const float* __restrict__ beta, const int* __restrict__ idx_ws,
    float* __restrict__ out)
{
    __shared__ FusedSmem sm;
    const int t = threadIdx.x;               // 0..511
    const int row0 = blockIdx.x * MTILE;
    const int b = row0 / (LQ*KQ);            // tiles never straddle b (30720 % 128 == 0)

    if (t < MTILE) {
        int rg = row0 + t;
        int rem = rg - b*(LQ*KQ);
        int i = rem / KQ;
        int j = idx_ws[rg];
        sm.residg[t]       = b*LQ + i;
        sm.residg[MTILE+t] = b*LQ + j;
        sm.drow[t] = (float)j - (float)i;
    }
    if (t < EFQ) { sm.gsh[t] = gamma[t]; sm.bsh[t] = beta[t]; }
    __syncthreads();

    const int w = t >> 6, lane = t & 63, q = lane >> 4, l15 = lane & 15;

    // ---- B staging (XOR-swizzled, dbuf). Thread t stages 16B: LDS row
    // n = t>>2, 16B-slot = t&3 (linear by lane, as global_load_lds requires).
    // LDS[n][slot] holds W[n][k-slot (slot ^ (n&3))] so reads of k-slot q use
    // LDS slot q ^ (n&3) -> 2-way bank aliasing only (free).
    const int sn = t >> 2, sslot = t & 3;
    const _Float16* stSrc = wpad + (size_t)sn*KPAD + ((sslot ^ (sn & 3)) * 8);
    auto stage = [&](int c) {
        __builtin_amdgcn_global_load_lds(
            (const __attribute__((address_space(1))) uint32_t*)(stSrc + c*32),
            (__attribute__((address_space(3))) uint32_t*)&sm.Bl[((c & 1) << 12) + (w << 9)],
            16, 0, 0);
    };
    stage(0);                                // in flight through the prologue

    // stage atoms: fp32 global -> packed f16 LDS (x,y,z,0 per slot)
    for (int u2 = t; u2 < 256*14; u2 += 512) {   // 7 exact iterations
        int s = u2 / 14; int a = u2 - s*14;
        const float* xp = X + (size_t)sm.residg[s]*42 + a*3;
        uint2 pk; pk.x = pkh(xp[0], xp[1]); pk.y = pkh(xp[2], 0.0f);
        *reinterpret_cast<uint2*>(&sm.atoms[s*56 + a*4]) = pk;
    }
    __syncthreads();

    if (t < 256) {   // Cb into slot 4 + mask bits, one residue each
        unsigned short* at = &sm.atoms[t*56];
        auto ld3 = [&](int slot, float& x, float& y, float& z) {
            half2t p0 = *reinterpret_cast<const half2t*>(at + slot*4);
            half2t p1 = *reinterpret_cast<const half2t*>(at + slot*4 + 2);
            x = (float)p0[0]; y = (float)p0[1]; z = (float)p1[0];
        };
        float Nx,Ny,Nz, Cax,Cay,Caz, Cx,Cy,Cz;
        ld3(0, Nx,Ny,Nz); ld3(1, Cax,Cay,Caz); ld3(2, Cx,Cy,Cz);
        float bx=Cax-Nx, by=Cay-Ny, bz=Caz-Nz;
        float ex=Cx-Cax, ey=Cy-Cay, ez=Cz-Caz;
        float ax = by*ez - bz*ey, ay = bz*ex - bx*ez, az = bx*ey - by*ex;
        float cbx = -0.58273431f*ax + 0.56802827f*bx - 0.54067466f*ex + Cax;
        float cby = -0.58273431f*ay + 0.56802827f*by - 0.54067466f*ey + Cay;
        float cbz = -0.58273431f*az + 0.56802827f*bz - 0.54067466f*ez + Caz;
        uint2 pk; pk.x = pkh(cbx, cby); pk.y = pkh(cbz, 0.0f);
        *reinterpret_cast<uint2*>(at + 4*4) = pk;    // slot 4 = Cb
        unsigned mb = 0;
        const float* amp = &atom_mask[(size_t)sm.residg[t]*AQ];
        #pragma unroll
        for (int a = 0; a < AQ; ++a) if (amp[a] > 0.5f) mb |= (1u << a);
        sm.maskb[t] = mb;
    }
    // NOTE: no barrier here -- the loop-top barrier covers Cb/maskb + stage(0).

    const int wr = w >> 1, wc = w & 1;        // 4 row-groups x 2 col-halves
    const int m0 = wr*32 + l15, m1 = m0 + 16; // the wave's two 16-row groups
    // B-frag halfword offset: n = wc*64 + nt*16 + l15, k-slot q -> LDS slot
    // q ^ (n&3) = q ^ (l15&3); nt contributes nt*512 (folds into ds imm).
    const int cst = ((wc*64 + l15) << 5) + ((q ^ (l15 & 3)) << 3);

    const unsigned short* atomsA0 = &sm.atoms[m0*56];
    const unsigned short* atomsB0 = &sm.atoms[(MTILE+m0)*56];
    const unsigned short* atomsA1 = &sm.atoms[m1*56];
    const unsigned short* atomsB1 = &sm.atoms[(MTILE+m1)*56];

    floatx4 acc0[4], acc1[4];
    #pragma unroll
    for (int nt = 0; nt < 4; ++nt) {
        acc0[nt] = (floatx4){0.f,0.f,0.f,0.f};
        acc1[nt] = (floatx4){0.f,0.f,0.f,0.f};
    }

    union H8 { uint32_t u[4]; half8 h; };
    unsigned maskA0 = 0, maskB0 = 0, maskA1 = 0, maskB1 = 0;
    float drow0 = 0.f, drow1 = 0.f;
    bool first = true;

    for (int c = 0; c < NCHUNK2; ++c) {
        __syncthreads();                      // buf[c&1] staged (drain issued a
                                              // full chunk ago); prev reads of
                                              // buf[(c+1)&1] complete.
        if (first) {                          // after barrier: maskb/drow valid
            maskA0 = sm.maskb[m0]; maskB0 = sm.maskb[MTILE+m0];
            maskA1 = sm.maskb[m1]; maskB1 = sm.maskb[MTILE+m1];
            drow0 = sm.drow[m0];   drow1 = sm.drow[m1];
            first = false;
        }
        if (c < NCHUNK2-1) stage(c+1);        // async, lands during this chunk
        H8 a0, a1;
        gen8(atomsA0, atomsB0, maskA0, maskB0, drow0, c*32 + q*8, a0.u);
        gen8(atomsA1, atomsB1, maskA1, maskB1, drow1, c*32 + q*8, a1.u);
        const unsigned short* Bb = &sm.Bl[(c & 1) << 12];
        #pragma unroll
        for (int nt = 0; nt < 4; ++nt) {
            half8 bv = *reinterpret_cast<const half8*>(&Bb[(nt << 9) + cst]);
            acc0[nt] = __builtin_amdgcn_mfma_f32_16x16x32_f16(a0.h, bv, acc0[nt], 0, 0, 0);
            acc1[nt] = __builtin_amdgcn_mfma_f32_16x16x32_f16(a1.h, bv, acc1[nt], 0, 0, 0);
        }
    }

    // LayerNorm epilogue with cross-wave (col-half) partial exchange.
    // C/D layout: col = lane&15, row = quad*4 + reg.
    auto lnpart = [&](const floatx4* acc, int g) {
        #pragma unroll
        for (int v = 0; v < 4; ++v) {
            float s = 0.f, s2 = 0.f;
            #pragma unroll
            for (int nt = 0; nt < 4; ++nt) { float x = acc[nt][v]; s += x; s2 += x*x; }
            #pragma unroll
            for (int off = 1; off < 16; off <<= 1) {
                s  += __shfl_xor(s,  off);
                s2 += __shfl_xor(s2, off);
            }
            int row_l = wr*32 + g*16 + q*4 + v;
            if (l15 == 0) { sm.part[row_l][wc] = s; sm.part2[row_l][wc] = s2; }
        }
    };
    lnpart(acc0, 0);
    lnpart(acc1, 1);
    __syncthreads();
    auto lnwrite = [&](const floatx4* acc, int g) {
        #pragma unroll
        for (int v = 0; v < 4; ++v) {
            int row_l = wr*32 + g*16 + q*4 + v;
            float s  = sm.part[row_l][0]  + sm.part[row_l][1];
            float s2 = sm.part2[row_l][0] + sm.part2[row_l][1];
            float mean = s * (1.0f/128.0f);
            float var  = s2 * (1.0f/128.0f) - mean*mean;
            float rstd = 1.0f / sqrtf(var + 1e-5f);
            size_t obase = (size_t)(row0 + row_l)*EFQ;
            #pragma unroll
            for (int nt = 0; nt < 4; ++nt) {
                int col = wc*64 + nt*16 + l15;
                out[obase + col] = (acc[nt][v] - mean)*rstd*sm.gsh[col] + sm.bsh[col];
            }
        }
    };
    lnwrite(acc0, 0);
    lnwrite(acc1, 1);
}

extern "C" void kernel_launch(void* const* d_in, const int* in_sizes, int n_in,
                              void* d_out, int out_size, void* d_ws, size_t ws_size,
                              hipStream_t stream)
{
    const float* X         = (const float*)d_in[0];
    const float* mask      = (const float*)d_in[1];
    // d_in[2] residue_idx, d_in[3] chain_labels: unused by the reference math
    const float* atom_mask = (const float*)d_in[4];
    const float* W         = (const float*)d_in[5];
    const float* gamma     = (const float*)d_in[6];
    const float* beta      = (const float*)d_in[7];
    float* out = (float*)d_out;

    int*       idx_ws = (int*)d_ws;                               // 61440*4 B
    _Float16*  wpad   = (_Float16*)((char*)d_ws + 262144);        // 128*3200*2 B

    hipLaunchKernelGGL(topk_kernel, dim3(306), dim3(512), 0, stream,
                       X, mask, W, out, idx_ws, wpad);
    hipLaunchKernelGGL(fused_kernel, dim3(ROWS/MTILE), dim3(512), 0, stream,
                       X, atom_mask, wpad, gamma, beta, idx_ws, out);
}

// Round 4
// 213.978 us; speedup vs baseline: 1.4340x; 1.0297x over previous
//
#include <hip/hip_runtime.h>
#include <hip/hip_bf16.h>
#include <stdint.h>

#define LQ 1024
#define BQ 2
#define AQ 14
#define KQ 30
#define EFQ 128
#define EDGE_IN 3152
#define KPAD 3200
#define NCHUNK 50
#define MTILE 128
#define ROWS (BQ*LQ*KQ)            /* 61440 */
#define EIDX_OFF (ROWS*EFQ)        /* 7864320 */

typedef __attribute__((ext_vector_type(8))) _Float16 half8;
typedef __attribute__((ext_vector_type(2))) _Float16 half2t;
typedef __attribute__((ext_vector_type(4))) float floatx4;
typedef unsigned long long ull;

static __device__ __forceinline__ uint32_t pkh(float a, float b) {
    auto h = __builtin_amdgcn_cvt_pkrtz(a, b);   // __fp16 ext_vector(2)
    return __builtin_bit_cast(uint32_t, h);
}
static __device__ __forceinline__ ull umin64(ull a, ull b) { return a < b ? a : b; }

// ---------------------------------------------------------------------------
// Kernel A v6 (unchanged): blocks 0..255 topk (8 rows/block, one wave per row,
// u64-packed keys); blocks 256..305: W fp32 -> f16 padded copy.
// ---------------------------------------------------------------------------
__global__ __launch_bounds__(512) void topk_kernel(
    const float* __restrict__ X, const float* __restrict__ mask,
    const float* __restrict__ W, float* __restrict__ out,
    int* __restrict__ idx_ws, _Float16* __restrict__ wpad)
{
    __shared__ float xs[LQ], ys[LQ], zs[LQ], ms[LQ];
    const int t = threadIdx.x;

    if (blockIdx.x >= 256) {                    // ---- merged wpad ----
        int base = (blockIdx.x - 256)*8192 + t; // 50 blocks x 8192 = 409600 exact
        #pragma unroll
        for (int r = 0; r < 16; ++r) {
            int idx = base + r*512;
            int n = idx / KPAD, f = idx - n*KPAD;
            float v = (f < EDGE_IN) ? W[(size_t)n*EDGE_IN + f] : 0.0f;
            wpad[idx] = (_Float16)v;
        }
        return;
    }

    const int w = t >> 6, lane = t & 63;
    const int row = blockIdx.x*8 + w;           // same b for whole block
    const int b = row >> 10, i = row & (LQ - 1);

    for (int j = t; j < LQ; j += 512) {
        size_t base = ((size_t)(b*LQ + j))*42 + 3;   // atom 1 (CA)
        xs[j] = X[base+0]; ys[j] = X[base+1]; zs[j] = X[base+2];
        ms[j] = mask[b*LQ + j];
    }
    __syncthreads();

    const float mif = ms[i];
    const double cx = (double)xs[i], cy = (double)ys[i], cz = (double)zs[i];

    double Dk[16]; float mf[16];
    bool allone = (mif == 1.0f);
    #pragma unroll
    for (int s = 0; s < 16; ++s) {
        int j = s*64 + lane;
        double dx = __dsub_rn(cx, (double)xs[j]);
        double dy = __dsub_rn(cy, (double)ys[j]);
        double dz = __dsub_rn(cz, (double)zs[j]);
        mf[s] = ms[j];
        Dk[s] = __dadd_rn(__dadd_rn(__dmul_rn(dx,dx), __dmul_rn(dy,dy)),
                          __dmul_rn(dz,dz));
        allone = allone && (mf[s] == 1.0f);
    }

    if (!__all(allone ? 1 : 0)) {
        // exact general path: D = mi*mj*sqrt(ssq+1e-6); key = D + 2(1-m2)*max(D)
        const double mi_d = (double)mif;
        double lm = 0.0;
        #pragma unroll
        for (int s = 0; s < 16; ++s) {
            double m2 = __dmul_rn(mi_d, (double)mf[s]);
            Dk[s] = __dmul_rn(m2, sqrt(__dadd_rn(Dk[s], 1e-6)));
            lm = fmax(lm, Dk[s]);
        }
        #pragma unroll
        for (int off = 32; off; off >>= 1) lm = fmax(lm, __shfl_xor(lm, off));
        #pragma unroll
        for (int s = 0; s < 16; ++s) {
            double m2 = __dmul_rn(mi_d, (double)mf[s]);
            Dk[s] = __dadd_rn(Dk[s],
                    __dmul_rn(__dmul_rn(2.0, __dsub_rn(1.0, m2)), lm));
        }
    }

    ull key[16];
    #pragma unroll
    for (int s = 0; s < 16; ++s)
        key[s] = (((ull)__double_as_longlong(Dk[s])) & ~1023ull)
               | (unsigned)(s*64 + lane);

    for (int k = 0; k < KQ; ++k) {
        ull a0 = umin64(key[0],  key[1]),  a1 = umin64(key[2],  key[3]);
        ull a2 = umin64(key[4],  key[5]),  a3 = umin64(key[6],  key[7]);
        ull a4 = umin64(key[8],  key[9]),  a5 = umin64(key[10], key[11]);
        ull a6 = umin64(key[12], key[13]), a7 = umin64(key[14], key[15]);
        ull b0 = umin64(a0, a1), b1 = umin64(a2, a3);
        ull b2 = umin64(a4, a5), b3 = umin64(a6, a7);
        ull bk = umin64(umin64(b0, b1), umin64(b2, b3));
        #pragma unroll
        for (int off = 32; off; off >>= 1)
            bk = umin64(bk, (ull)__shfl_xor(bk, off));
        int j = (int)(bk & 1023ull);
        if (lane == 0) {
            int rg = row*KQ + k;
            idx_ws[rg] = j;
            out[EIDX_OFF + rg] = (float)j;
        }
        bool mine = ((j & 63) == lane);
        int s_win = j >> 6;
        #pragma unroll
        for (int s = 0; s < 16; ++s)
            key[s] = (mine && s == s_win) ? ~0ull : key[s];
    }
}

// ---------------------------------------------------------------------------
// Kernel B v11 = v7 skeleton + column-split waves.
// 512 threads = 8 waves arranged 4 row-groups x 2 col-halves; each wave owns
// 32 rows x 64 cols -> per-chunk B LDS reads halve vs v7 (64 vs 128 b128),
// feature-gen duplicates 2x (VALU has 4x headroom). Everything else is v7
// verbatim: K-chunk 64, 2 barriers/chunk, identical staging + 8-slot XOR
// swizzle (the pattern measured conflict-free), no min-waves bound.
// LDS 50.7 KB -> 3 blocks/CU (24 waves/CU).
// ---------------------------------------------------------------------------
struct FusedSmem {
    alignas(16) unsigned short atoms[256*56];  // f16 x,y,z,pad x 14 slots; 0..127 center, 128..255 neighbor
    alignas(16) unsigned short Bl[128*64];     // W chunk (f16 bits), XOR-swizzled (v7 layout)
    alignas(16) float drow[MTILE];
    alignas(16) float part[MTILE][2];          // LN partial sums per col-half
    alignas(16) float part2[MTILE][2];
    int residg[256];
    unsigned int maskb[256];
    float gsh[EFQ], bsh[EFQ];
};                                             // 50,688 B -> 3 blocks/CU

// Generate 8 contiguous features [f0, f0+8) for one row as 4 packed f16
// dwords. RBF: exp(-((d - r*4/3)*0.8)^2) = exp2(-(u - r*v)^2),
// u = d*0.96089846, v = 1.28119795. Dead pairs (mask or pad) poison u so all
// eight exp2 underflow to exact +0.
static __device__ __forceinline__ void gen8(
    const unsigned short* __restrict__ atomsA,
    const unsigned short* __restrict__ atomsB,
    unsigned maskA, unsigned maskB, float drowv,
    int f0, uint32_t* __restrict__ v)
{
    if (f0 >= 16) {
        int p = (f0 - 16) >> 4;
        int rbase = (f0 - 16) & 15;                 // == (q&1)*8
        int pc = p > 195 ? 195 : p;                 // clamp pad region to valid slot
        int a  = (pc * 74899) >> 20;                // pc / 14 for pc < 2048
        int bp = pc - a*14;
        bool dead = (p > 195) |
                    ((((maskA >> a) | (maskB >> bp)) & 1u) != 0u);
        half2t c0 = *reinterpret_cast<const half2t*>(atomsA + a*4);
        half2t c1 = *reinterpret_cast<const half2t*>(atomsA + a*4 + 2);
        half2t n0 = *reinterpret_cast<const half2t*>(atomsB + bp*4);
        half2t n1 = *reinterpret_cast<const half2t*>(atomsB + bp*4 + 2);
        half2t dxy = c0 - n0;                        // v_pk_add_f16
        half2t dzw = c1 - n1;
        float dx = (float)dxy[0], dy = (float)dxy[1], dz = (float)dzw[0];
        float u = __builtin_amdgcn_sqrtf(dx*dx + dy*dy + dz*dz + 1e-6f) * 0.96089846f;
        u = dead ? 1.0e4f : u;                       // exp2(-(~1e4)^2) -> +0 exactly
        #pragma unroll
        for (int k = 0; k < 4; ++k) {
            float t0 = __fmaf_rn(-(float)(rbase + 2*k),     1.28119795f, u);
            float t1 = __fmaf_rn(-(float)(rbase + 2*k + 1), 1.28119795f, u);
            v[k] = pkh(__builtin_amdgcn_exp2f(-(t0*t0)),
                       __builtin_amdgcn_exp2f(-(t1*t1)));
        }
    } else {
        const float fr[8] = {1.0f, 0.31622776601683794f, 0.1f,
            0.031622776601683794f, 0.01f, 0.0031622776601683794f,
            0.001f, 0.00031622776601683794f};
        float e[8];
        if (f0 == 0) {
            #pragma unroll
            for (int j = 0; j < 8; ++j) e[j] = __cosf(drowv * fr[j]);
        } else {
            #pragma unroll
            for (int j = 0; j < 8; ++j) e[j] = __sinf(drowv * fr[j]);
        }
        #pragma unroll
        for (int k = 0; k < 4; ++k) v[k] = pkh(e[2*k], e[2*k+1]);
    }
}

__global__ __launch_bounds__(512, 4) void fused_kernel(
    const float* __restrict__ X, const float* __restrict__ atom_mask,
    const _Float16* __restrict__ wpad, const float* __restrict__ gamma,
    const float* __restrict__ beta, const int* __restrict__ idx_ws,
    float* __restrict__ out)
{
    __shared__ FusedSmem sm;
    const int t = threadIdx.x;               // 0..511
    const int row0 = blockIdx.x * MTILE;
    const int b = row0 / (LQ*KQ);            // tiles never straddle b (30720 % 128 == 0)

    if (t < MTILE) {
        int rg = row0 + t;
        int rem = rg - b*(LQ*KQ);
        int i = rem / KQ;
        int j = idx_ws[rg];
        sm.residg[t]       = b*LQ + i;
        sm.residg[MTILE+t] = b*LQ + j;
        sm.drow[t] = (float)j - (float)i;
    }
    if (t < EFQ) { sm.gsh[t] = gamma[t]; sm.bsh[t] = beta[t]; }
    __syncthreads();

    // stage atoms: fp32 global -> packed f16 LDS (x,y,z,0 per slot)
    for (int u2 = t; u2 < 256*14; u2 += 512) {   // 7 exact iterations
        int s = u2 / 14; int a = u2 - s*14;
        const float* xp = X + (size_t)sm.residg[s]*42 + a*3;
        uint2 pk; pk.x = pkh(xp[0], xp[1]); pk.y = pkh(xp[2], 0.0f);
        *reinterpret_cast<uint2*>(&sm.atoms[s*56 + a*4]) = pk;
    }
    __syncthreads();

    if (t < 256) {   // Cb into slot 4 + mask bits, one residue each
        unsigned short* at = &sm.atoms[t*56];
        auto ld3 = [&](int slot, float& x, float& y, float& z) {
            half2t p0 = *reinterpret_cast<const half2t*>(at + slot*4);
            half2t p1 = *reinterpret_cast<const half2t*>(at + slot*4 + 2);
            x = (float)p0[0]; y = (float)p0[1]; z = (float)p1[0];
        };
        float Nx,Ny,Nz, Cax,Cay,Caz, Cx,Cy,Cz;
        ld3(0, Nx,Ny,Nz); ld3(1, Cax,Cay,Caz); ld3(2, Cx,Cy,Cz);
        float bx=Cax-Nx, by=Cay-Ny, bz=Caz-Nz;
        float ex=Cx-Cax, ey=Cy-Cay, ez=Cz-Caz;
        float ax = by*ez - bz*ey, ay = bz*ex - bx*ez, az = bx*ey - by*ex;
        float cbx = -0.58273431f*ax + 0.56802827f*bx - 0.54067466f*ex + Cax;
        float cby = -0.58273431f*ay + 0.56802827f*by - 0.54067466f*ey + Cay;
        float cbz = -0.58273431f*az + 0.56802827f*bz - 0.54067466f*ez + Caz;
        uint2 pk; pk.x = pkh(cbx, cby); pk.y = pkh(cbz, 0.0f);
        *reinterpret_cast<uint2*>(at + 4*4) = pk;    // slot 4 = Cb
        unsigned mb = 0;
        const float* amp = &atom_mask[(size_t)sm.residg[t]*AQ];
        #pragma unroll
        for (int a = 0; a < AQ; ++a) if (amp[a] > 0.5f) mb |= (1u << a);
        sm.maskb[t] = mb;
    }

    const int w = t >> 6, lane = t & 63, q = lane >> 4, l15 = lane & 15;
    const int wr = w >> 1, wc = w & 1;        // 4 row-groups x 2 col-halves
    const int m0 = wr*32 + l15, m1 = m0 + 16; // the wave's two 16-row groups

    // ---- loop-invariant hoists (v7 swizzle, n now spans the col-half) ----
    int boff0[4], boff1[4];                   // B-frag LDS offsets (XOR swizzle)
    #pragma unroll
    for (int nt = 0; nt < 4; ++nt) {
        int n = wc*64 + nt*16 + l15;
        boff0[nt] = n*64 + ((q ^ (n&7))*8);
        boff1[nt] = n*64 + (((4+q) ^ (n&7))*8);
    }
    int stRegion[2]; const _Float16* stBase[2];   // staging: v7 verbatim
    #pragma unroll
    for (int i2 = 0; i2 < 2; ++i2) {
        int region = w*2 + i2;                        // 16 regions x 8 rows
        int n = region*8 + (lane >> 3);
        int kbsrc = (lane & 7) ^ (lane >> 3);
        stRegion[i2] = region;
        stBase[i2] = wpad + (size_t)n*KPAD + kbsrc*8;
    }
    auto stage = [&](int c) {
        #pragma unroll
        for (int i2 = 0; i2 < 2; ++i2) {
            const _Float16* g = stBase[i2] + c*64;
            __builtin_amdgcn_global_load_lds(
                (const __attribute__((address_space(1))) uint32_t*)g,
                (__attribute__((address_space(3))) uint32_t*)&sm.Bl[stRegion[i2]*512],
                16, 0, 0);
        }
    };

    floatx4 acc0[4], acc1[4];
    #pragma unroll
    for (int nt = 0; nt < 4; ++nt) {
        acc0[nt] = (floatx4){0.f,0.f,0.f,0.f};
        acc1[nt] = (floatx4){0.f,0.f,0.f,0.f};
    }

    __syncthreads();                          // atoms/maskb ready

    const unsigned short* atomsA0 = &sm.atoms[m0*56];
    const unsigned short* atomsB0 = &sm.atoms[(MTILE+m0)*56];
    const unsigned short* atomsA1 = &sm.atoms[m1*56];
    const unsigned short* atomsB1 = &sm.atoms[(MTILE+m1)*56];
    const unsigned maskA0 = sm.maskb[m0], maskB0 = sm.maskb[MTILE+m0];
    const unsigned maskA1 = sm.maskb[m1], maskB1 = sm.maskb[MTILE+m1];
    const float drow0 = sm.drow[m0], drow1 = sm.drow[m1];

    union H8 { uint32_t u[4]; half8 h; };
    for (int c = 0; c < NCHUNK; ++c) {
        if (c) __syncthreads();               // all reads of previous B chunk done
        stage(c);                             // async global->LDS, in flight during gen
        H8 a00, a01, a10, a11;
        gen8(atomsA0, atomsB0, maskA0, maskB0, drow0, c*64 + q*8,      a00.u);
        gen8(atomsA0, atomsB0, maskA0, maskB0, drow0, c*64 + 32 + q*8, a01.u);
        gen8(atomsA1, atomsB1, maskA1, maskB1, drow1, c*64 + q*8,      a10.u);
        gen8(atomsA1, atomsB1, maskA1, maskB1, drow1, c*64 + 32 + q*8, a11.u);
        __syncthreads();                      // drains vmcnt: Bl ready
        #pragma unroll
        for (int nt = 0; nt < 4; ++nt) {
            half8 b0 = *reinterpret_cast<const half8*>(&sm.Bl[boff0[nt]]);
            half8 b1 = *reinterpret_cast<const half8*>(&sm.Bl[boff1[nt]]);
            acc0[nt] = __builtin_amdgcn_mfma_f32_16x16x32_f16(a00.h, b0, acc0[nt], 0, 0, 0);
            acc0[nt] = __builtin_amdgcn_mfma_f32_16x16x32_f16(a01.h, b1, acc0[nt], 0, 0, 0);
            acc1[nt] = __builtin_amdgcn_mfma_f32_16x16x32_f16(a10.h, b0, acc1[nt], 0, 0, 0);
            acc1[nt] = __builtin_amdgcn_mfma_f32_16x16x32_f16(a11.h, b1, acc1[nt], 0, 0, 0);
        }
    }

    // LayerNorm epilogue with cross-wave (col-half) partial exchange.
    // C/D layout: col = lane&15, row = quad*4 + reg.
    auto lnpart = [&](const floatx4* acc, int g) {
        #pragma unroll
        for (int v = 0; v < 4; ++v) {
            float s = 0.f, s2 = 0.f;
            #pragma unroll
            for (int nt = 0; nt < 4; ++nt) { float x = acc[nt][v]; s += x; s2 += x*x; }
            #pragma unroll
            for (int off = 1; off < 16; off <<= 1) {
                s  += __shfl_xor(s,  off);
                s2 += __shfl_xor(s2, off);
            }
            int row_l = wr*32 + g*16 + q*4 + v;
            if (l15 == 0) { sm.part[row_l][wc] = s; sm.part2[row_l][wc] = s2; }
        }
    };
    lnpart(acc0, 0);
    lnpart(acc1, 1);
    __syncthreads();
    auto lnwrite = [&](const floatx4* acc, int g) {
        #pragma unroll
        for (int v = 0; v < 4; ++v) {
            int row_l = wr*32 + g*16 + q*4 + v;
            float s  = sm.part[row_l][0]  + sm.part[row_l][1];
            float s2 = sm.part2[row_l][0] + sm.part2[row_l][1];
            float mean = s * (1.0f/128.0f);
            float var  = s2 * (1.0f/128.0f) - mean*mean;
            float rstd = 1.0f / sqrtf(var + 1e-5f);
            size_t obase = (size_t)(row0 + row_l)*EFQ;
            #pragma unroll
            for (int nt = 0; nt < 4; ++nt) {
                int col = wc*64 + nt*16 + l15;
                out[obase + col] = (acc[nt][v] - mean)*rstd*sm.gsh[col] + sm.bsh[col];
            }
        }
    };
    lnwrite(acc0, 0);
    lnwrite(acc1, 1);
}

extern "C" void kernel_launch(void* const* d_in, const int* in_sizes, int n_in,
                              void* d_out, int out_size, void* d_ws, size_t ws_size,
                              hipStream_t stream)
{
    const float* X         = (const float*)d_in[0];
    const float* mask      = (const float*)d_in[1];
    // d_in[2] residue_idx, d_in[3] chain_labels: unused by the reference math
    const float* atom_mask = (const float*)d_in[4];
    const float* W         = (const float*)d_in[5];
    const float* gamma     = (const float*)d_in[6];
    const float* beta      = (const float*)d_in[7];
    float* out = (float*)d_out;

    int*       idx_ws = (int*)d_ws;                               // 61440*4 B
    _Float16*  wpad   = (_Float16*)((char*)d_ws + 262144);        // 128*3200*2 B

    hipLaunchKernelGGL(topk_kernel, dim3(306), dim3(512), 0, stream,
                       X, mask, W, out, idx_ws, wpad);
    hipLaunchKernelGGL(fused_kernel, dim3(ROWS/MTILE), dim3(512), 0, stream,
                       X, atom_mask, wpad, gamma, beta, idx_ws, out);
}

// Round 5
// 170.195 us; speedup vs baseline: 1.8029x; 1.2572x over previous
//
#include <hip/hip_runtime.h>
#include <hip/hip_bf16.h>
#include <stdint.h>

#define LQ 1024
#define BQ 2
#define AQ 14
#define KQ 30
#define EFQ 128
#define EDGE_IN 3152
#define KPAD 3200
#define NCHUNK 50
#define MTILE 128
#define ROWS (BQ*LQ*KQ)            /* 61440 */
#define EIDX_OFF (ROWS*EFQ)        /* 7864320 */

typedef __attribute__((ext_vector_type(8))) _Float16 half8;
typedef __attribute__((ext_vector_type(2))) _Float16 half2t;
typedef __attribute__((ext_vector_type(4))) float floatx4;
typedef unsigned long long ull;

static __device__ __forceinline__ uint32_t pkh(float a, float b) {
    auto h = __builtin_amdgcn_cvt_pkrtz(a, b);   // __fp16 ext_vector(2)
    return __builtin_bit_cast(uint32_t, h);
}
static __device__ __forceinline__ ull umin64(ull a, ull b) { return a < b ? a : b; }

// ---------------------------------------------------------------------------
// Kernel A v6 (unchanged): blocks 0..255 topk (8 rows/block, one wave per row,
// u64-packed keys); blocks 256..305: W fp32 -> f16 padded copy.
// ---------------------------------------------------------------------------
__global__ __launch_bounds__(512) void topk_kernel(
    const float* __restrict__ X, const float* __restrict__ mask,
    const float* __restrict__ W, float* __restrict__ out,
    int* __restrict__ idx_ws, _Float16* __restrict__ wpad)
{
    __shared__ float xs[LQ], ys[LQ], zs[LQ], ms[LQ];
    const int t = threadIdx.x;

    if (blockIdx.x >= 256) {                    // ---- merged wpad ----
        int base = (blockIdx.x - 256)*8192 + t; // 50 blocks x 8192 = 409600 exact
        #pragma unroll
        for (int r = 0; r < 16; ++r) {
            int idx = base + r*512;
            int n = idx / KPAD, f = idx - n*KPAD;
            float v = (f < EDGE_IN) ? W[(size_t)n*EDGE_IN + f] : 0.0f;
            wpad[idx] = (_Float16)v;
        }
        return;
    }

    const int w = t >> 6, lane = t & 63;
    const int row = blockIdx.x*8 + w;           // same b for whole block
    const int b = row >> 10, i = row & (LQ - 1);

    for (int j = t; j < LQ; j += 512) {
        size_t base = ((size_t)(b*LQ + j))*42 + 3;   // atom 1 (CA)
        xs[j] = X[base+0]; ys[j] = X[base+1]; zs[j] = X[base+2];
        ms[j] = mask[b*LQ + j];
    }
    __syncthreads();

    const float mif = ms[i];
    const double cx = (double)xs[i], cy = (double)ys[i], cz = (double)zs[i];

    double Dk[16]; float mf[16];
    bool allone = (mif == 1.0f);
    #pragma unroll
    for (int s = 0; s < 16; ++s) {
        int j = s*64 + lane;
        double dx = __dsub_rn(cx, (double)xs[j]);
        double dy = __dsub_rn(cy, (double)ys[j]);
        double dz = __dsub_rn(cz, (double)zs[j]);
        mf[s] = ms[j];
        Dk[s] = __dadd_rn(__dadd_rn(__dmul_rn(dx,dx), __dmul_rn(dy,dy)),
                          __dmul_rn(dz,dz));
        allone = allone && (mf[s] == 1.0f);
    }

    if (!__all(allone ? 1 : 0)) {
        // exact general path: D = mi*mj*sqrt(ssq+1e-6); key = D + 2(1-m2)*max(D)
        const double mi_d = (double)mif;
        double lm = 0.0;
        #pragma unroll
        for (int s = 0; s < 16; ++s) {
            double m2 = __dmul_rn(mi_d, (double)mf[s]);
            Dk[s] = __dmul_rn(m2, sqrt(__dadd_rn(Dk[s], 1e-6)));
            lm = fmax(lm, Dk[s]);
        }
        #pragma unroll
        for (int off = 32; off; off >>= 1) lm = fmax(lm, __shfl_xor(lm, off));
        #pragma unroll
        for (int s = 0; s < 16; ++s) {
            double m2 = __dmul_rn(mi_d, (double)mf[s]);
            Dk[s] = __dadd_rn(Dk[s],
                    __dmul_rn(__dmul_rn(2.0, __dsub_rn(1.0, m2)), lm));
        }
    }

    ull key[16];
    #pragma unroll
    for (int s = 0; s < 16; ++s)
        key[s] = (((ull)__double_as_longlong(Dk[s])) & ~1023ull)
               | (unsigned)(s*64 + lane);

    for (int k = 0; k < KQ; ++k) {
        ull a0 = umin64(key[0],  key[1]),  a1 = umin64(key[2],  key[3]);
        ull a2 = umin64(key[4],  key[5]),  a3 = umin64(key[6],  key[7]);
        ull a4 = umin64(key[8],  key[9]),  a5 = umin64(key[10], key[11]);
        ull a6 = umin64(key[12], key[13]), a7 = umin64(key[14], key[15]);
        ull b0 = umin64(a0, a1), b1 = umin64(a2, a3);
        ull b2 = umin64(a4, a5), b3 = umin64(a6, a7);
        ull bk = umin64(umin64(b0, b1), umin64(b2, b3));
        #pragma unroll
        for (int off = 32; off; off >>= 1)
            bk = umin64(bk, (ull)__shfl_xor(bk, off));
        int j = (int)(bk & 1023ull);
        if (lane == 0) {
            int rg = row*KQ + k;
            idx_ws[rg] = j;
            out[EIDX_OFF + rg] = (float)j;
        }
        bool mine = ((j & 63) == lane);
        int s_win = j >> 6;
        #pragma unroll
        for (int s = 0; s < 16; ++s)
            key[s] = (mine && s == s_win) ? ~0ull : key[s];
    }
}

// ---------------------------------------------------------------------------
// Kernel B v12 = v7 skeleton + issue-cycle trims + 1-barrier dbuf.
// Model (R4): SIMDs are issue-saturated (VALUBusy+MfmaUtil ~82% per SIMD in
// v7/v10/v11); LDS pipe is ~60% (256 B/clk read). So: keep v7's optimal work
// decomposition (8 waves x 16 rows x 128 cols, gen8 exactly once per feature)
// and cut VALU instructions + barrier drains:
//  - masked atoms poisoned to +/-30000 in LDS coords -> exp2 underflows to +0
//    (removes all per-call mask logic and the maskb array)
//  - coords pre-scaled by 0.96089846 at staging (after Cb); eps' = 9.2333e-7
//  - pair addressing via p0 = 4c-(q<2), p1 = p0+2, one magic-mul each
//  - double-buffered Bl, ONE __syncthreads per chunk at loop bottom (its
//    vmcnt(0) drain provides DMA visibility; stage(c+1) flies across the
//    whole gen+MFMA phase instead of gen only)
// LDS 64.0 KB -> capacity 2 blocks/CU; 480 blocks < 512 slots: residency
// unchanged vs v7.
// ---------------------------------------------------------------------------
struct FusedSmem {
    alignas(16) unsigned short atoms[256*56];  // 28672 B: f16 x,y,z,pad x 14 slots (scaled+poisoned)
    alignas(16) unsigned short Bl[2*8192];     // 32768 B: dbuf W chunk (f16), v7 XOR swizzle
    alignas(16) float drow[MTILE];             // 512
    int residg[256];                           // 1024
    float gsh[EFQ], bsh[EFQ];                  // 1024
};                                             // 64,000 B

// RBF features [8] for one (center-atom, neighbor-atom) pair, rbase folded
// into rboff: t_j = (|d|_scaled + rboff) - j*1.28119795; e = exp2(-t^2).
// Poisoned coords make |d| ~ 3e4..1e5 -> all eight exp2 give exact +0.
static __device__ __forceinline__ void gen_rbf(
    const char* __restrict__ rowA, const char* __restrict__ rowB,
    int ao, int bo, float rboff, uint32_t* __restrict__ v)
{
    uint2 ca = *reinterpret_cast<const uint2*>(rowA + ao);
    uint2 nb = *reinterpret_cast<const uint2*>(rowB + bo);
    half2t c0 = __builtin_bit_cast(half2t, ca.x);
    half2t c1 = __builtin_bit_cast(half2t, ca.y);
    half2t n0 = __builtin_bit_cast(half2t, nb.x);
    half2t n1 = __builtin_bit_cast(half2t, nb.y);
    half2t dxy = c0 - n0;                        // v_pk_add_f16
    half2t dzw = c1 - n1;
    float dx = (float)dxy[0], dy = (float)dxy[1], dz = (float)dzw[0];
    float ssq = __fmaf_rn(dx, dx, __fmaf_rn(dy, dy,
                __fmaf_rn(dz, dz, 9.2332585e-7f)));     // (1e-6 scaled)
    float u = __builtin_amdgcn_sqrtf(ssq) + rboff;
    const float CJ[8] = {0.0f, 1.28119795f, 2.5623959f, 3.84359385f,
                         5.1247918f, 6.40598975f, 7.6871877f, 8.96838565f};
    #pragma unroll
    for (int k = 0; k < 4; ++k) {
        float t0 = u - CJ[2*k];
        float t1 = u - CJ[2*k+1];
        v[k] = pkh(__builtin_amdgcn_exp2f(-(t0*t0)),
                   __builtin_amdgcn_exp2f(-(t1*t1)));
    }
}

__global__ __launch_bounds__(512) void fused_kernel(
    const float* __restrict__ X, const float* __restrict__ atom_mask,
    const _Float16* __restrict__ wpad, const float* __restrict__ gamma,
    const float* __restrict__ beta, const int* __restrict__ idx_ws,
    float* __restrict__ out)
{
    __shared__ FusedSmem sm;
    const int t = threadIdx.x;               // 0..511
    const int row0 = blockIdx.x * MTILE;
    const int b = row0 / (LQ*KQ);            // tiles never straddle b (30720 % 128 == 0)

    if (t < MTILE) {
        int rg = row0 + t;
        int rem = rg - b*(LQ*KQ);
        int i = rem / KQ;
        int j = idx_ws[rg];
        sm.residg[t]       = b*LQ + i;
        sm.residg[MTILE+t] = b*LQ + j;
        sm.drow[t] = (float)j - (float)i;
    }
    if (t < EFQ) { sm.gsh[t] = gamma[t]; sm.bsh[t] = beta[t]; }
    __syncthreads();

    const int w = t >> 6, lane = t & 63, q = lane >> 4, l15 = lane & 15;
    const int m = w*16 + l15;                 // tile-local row (0..127)

    // ---- staging hoists (v7 verbatim + dbuf select) ----------------------
    int stRegion[2]; const _Float16* stBase[2];
    #pragma unroll
    for (int i2 = 0; i2 < 2; ++i2) {
        int region = w*2 + i2;                        // 16 regions x 8 rows
        int n = region*8 + (lane >> 3);
        int kbsrc = (lane & 7) ^ (lane >> 3);
        stRegion[i2] = region;
        stBase[i2] = wpad + (size_t)n*KPAD + kbsrc*8;
    }
    auto stage = [&](int c) {
        #pragma unroll
        for (int i2 = 0; i2 < 2; ++i2) {
            const _Float16* g = stBase[i2] + c*64;
            __builtin_amdgcn_global_load_lds(
                (const __attribute__((address_space(1))) uint32_t*)g,
                (__attribute__((address_space(3))) uint32_t*)
                    &sm.Bl[((c & 1) << 13) + stRegion[i2]*512],
                16, 0, 0);
        }
    };
    stage(0);                                 // flies across the prologue

    // stage atoms: fp32 global -> packed f16 LDS (raw, x,y,z,0 per slot)
    for (int u2 = t; u2 < 256*14; u2 += 512) {   // 7 exact iterations
        int s = u2 / 14; int a = u2 - s*14;
        const float* xp = X + (size_t)sm.residg[s]*42 + a*3;
        uint2 pk; pk.x = pkh(xp[0], xp[1]); pk.y = pkh(xp[2], 0.0f);
        *reinterpret_cast<uint2*>(&sm.atoms[s*56 + a*4]) = pk;
    }
    __syncthreads();

    if (t < 256) {   // Cb (raw) into slot 4, then scale + mask-poison all 14
        unsigned short* at = &sm.atoms[t*56];
        auto ld3 = [&](int slot, float& x, float& y, float& z) {
            half2t p0 = *reinterpret_cast<const half2t*>(at + slot*4);
            half2t p1 = *reinterpret_cast<const half2t*>(at + slot*4 + 2);
            x = (float)p0[0]; y = (float)p0[1]; z = (float)p1[0];
        };
        float Nx,Ny,Nz, Cax,Cay,Caz, Cx,Cy,Cz;
        ld3(0, Nx,Ny,Nz); ld3(1, Cax,Cay,Caz); ld3(2, Cx,Cy,Cz);
        float bx=Cax-Nx, by=Cay-Ny, bz=Caz-Nz;
        float ex=Cx-Cax, ey=Cy-Cay, ez=Cz-Caz;
        float ax = by*ez - bz*ey, ay = bz*ex - bx*ez, az = bx*ey - by*ex;
        float cbx = -0.58273431f*ax + 0.56802827f*bx - 0.54067466f*ex + Cax;
        float cby = -0.58273431f*ay + 0.56802827f*by - 0.54067466f*ey + Cay;
        float cbz = -0.58273431f*az + 0.56802827f*bz - 0.54067466f*ez + Caz;
        uint2 pk4; pk4.x = pkh(cbx, cby); pk4.y = pkh(cbz, 0.0f);
        *reinterpret_cast<uint2*>(at + 4*4) = pk4;   // slot 4 = Cb (raw)

        const float P = (t < MTILE) ? 30000.0f : -30000.0f;  // center/neighbor
        const uint32_t pxx = pkh(P, P), pxy = pkh(P, 0.0f);
        half2t sc2; sc2[0] = (_Float16)0.96089846f; sc2[1] = (_Float16)0.96089846f;
        const float* amp = &atom_mask[(size_t)sm.residg[t]*AQ];
        #pragma unroll
        for (int a = 0; a < AQ; ++a) {
            uint2 vv = *reinterpret_cast<const uint2*>(at + a*4);
            half2t lo = __builtin_bit_cast(half2t, vv.x) * sc2;
            half2t hi = __builtin_bit_cast(half2t, vv.y) * sc2;
            bool msk = amp[a] > 0.5f;
            uint2 ov;
            ov.x = msk ? pxx : __builtin_bit_cast(uint32_t, lo);
            ov.y = msk ? pxy : __builtin_bit_cast(uint32_t, hi);
            *reinterpret_cast<uint2*>(at + a*4) = ov;
        }
    }

    // ---- B-read LDS offsets (v7 swizzle) ---------------------------------
    int boff0[8], boff1[8];
    #pragma unroll
    for (int nt = 0; nt < 8; ++nt) {
        int n = nt*16 + l15;
        boff0[nt] = n*64 + ((q ^ (n&7))*8);
        boff1[nt] = n*64 + (((4+q) ^ (n&7))*8);
    }

    const char* rowA = (const char*)&sm.atoms[m*56];
    const char* rowB = (const char*)&sm.atoms[(MTILE+m)*56];
    const int   qlt2  = (q < 2) ? 1 : 0;
    const float rboff = -(float)((q & 1) * 8) * 1.28119795f;

    floatx4 acc[8];
    #pragma unroll
    for (int nt = 0; nt < 8; ++nt) acc[nt] = (floatx4){0.f,0.f,0.f,0.f};

    __syncthreads();   // atoms scaled/poisoned visible; stage(0) drained

    union H8 { uint32_t u[4]; half8 h; };
    for (int c = 0; c < NCHUNK; ++c) {
        if (c < NCHUNK-1) stage(c+1);         // lands during gen+MFMA below

        // pair addressing: p0 = 4c - (q<2), p1 = p0 + 2; a = p/14, bp = p%14
        int p0 = 4*c - qlt2;
        int p1 = p0 + 2;
        int pa0 = (p0 * 74899) >> 20;  int pa1 = (p1 * 74899) >> 20;
        pa0 = pa0 > 13 ? 13 : pa0;     pa1 = pa1 > 13 ? 13 : pa1;
        int ao0 = pa0 << 3, bo0 = (p0 - pa0*14) << 3;
        int ao1 = pa1 << 3, bo1 = (p1 - pa1*14) << 3;

        H8 a00, a01;
        if (c == 0) {
            if (qlt2) {                        // positional features (f0 = 0 or 8)
                const float fr[8] = {1.0f, 0.31622776601683794f, 0.1f,
                    0.031622776601683794f, 0.01f, 0.0031622776601683794f,
                    0.001f, 0.00031622776601683794f};
                float dr = sm.drow[m];
                float e[8];
                if (q == 0) {
                    #pragma unroll
                    for (int j = 0; j < 8; ++j) e[j] = __cosf(dr * fr[j]);
                } else {
                    #pragma unroll
                    for (int j = 0; j < 8; ++j) e[j] = __sinf(dr * fr[j]);
                }
                #pragma unroll
                for (int k = 0; k < 4; ++k) a00.u[k] = pkh(e[2*k], e[2*k+1]);
            } else {
                gen_rbf(rowA, rowB, ao0, bo0, rboff, a00.u);
            }
        } else {
            gen_rbf(rowA, rowB, ao0, bo0, rboff, a00.u);
        }
        gen_rbf(rowA, rowB, ao1, bo1, rboff, a01.u);

        const unsigned short* Bb = &sm.Bl[(c & 1) << 13];
        #pragma unroll
        for (int nt = 0; nt < 8; ++nt) {
            half8 b0 = *reinterpret_cast<const half8*>(&Bb[boff0[nt]]);
            half8 b1 = *reinterpret_cast<const half8*>(&Bb[boff1[nt]]);
            acc[nt] = __builtin_amdgcn_mfma_f32_16x16x32_f16(a00.h, b0, acc[nt], 0, 0, 0);
            acc[nt] = __builtin_amdgcn_mfma_f32_16x16x32_f16(a01.h, b1, acc[nt], 0, 0, 0);
        }
        __syncthreads();   // drains my stage(c+1) DMA (vmcnt 0) + fences
                           // everyone's reads of Bl[c&1] before it is restaged
    }

    // LayerNorm epilogue. C/D layout: col = lane&15, row = quad*4 + reg.
    #pragma unroll
    for (int v = 0; v < 4; ++v) {
        float s = 0.f, s2 = 0.f;
        #pragma unroll
        for (int nt = 0; nt < 8; ++nt) { float x = acc[nt][v]; s += x; s2 += x*x; }
        #pragma unroll
        for (int off = 1; off < 16; off <<= 1) {
            s  += __shfl_xor(s,  off);
            s2 += __shfl_xor(s2, off);
        }
        float mean = s * (1.0f/128.0f);
        float var  = s2 * (1.0f/128.0f) - mean*mean;
        float rstd = 1.0f / sqrtf(var + 1e-5f);
        int row_l = w*16 + q*4 + v;
        size_t obase = (size_t)(row0 + row_l)*EFQ;
        #pragma unroll
        for (int nt = 0; nt < 8; ++nt) {
            int col = nt*16 + l15;
            out[obase + col] = (acc[nt][v] - mean)*rstd*sm.gsh[col] + sm.bsh[col];
        }
    }
}

extern "C" void kernel_launch(void* const* d_in, const int* in_sizes, int n_in,
                              void* d_out, int out_size, void* d_ws, size_t ws_size,
                              hipStream_t stream)
{
    const float* X         = (const float*)d_in[0];
    const float* mask      = (const float*)d_in[1];
    // d_in[2] residue_idx, d_in[3] chain_labels: unused by the reference math
    const float* atom_mask = (const float*)d_in[4];
    const float* W         = (const float*)d_in[5];
    const float* gamma     = (const float*)d_in[6];
    const float* beta      = (const float*)d_in[7];
    float* out = (float*)d_out;

    int*       idx_ws = (int*)d_ws;                               // 61440*4 B
    _Float16*  wpad   = (_Float16*)((char*)d_ws + 262144);        // 128*3200*2 B

    hipLaunchKernelGGL(topk_kernel, dim3(306), dim3(512), 0, stream,
                       X, mask, W, out, idx_ws, wpad);
    hipLaunchKernelGGL(fused_kernel, dim3(ROWS/MTILE), dim3(512), 0, stream,
                       X, atom_mask, wpad, gamma, beta, idx_ws, out);
}